// Round 9
// baseline (443.026 us; speedup 1.0000x reference)
//
#include <hip/hip_runtime.h>

typedef __attribute__((ext_vector_type(8))) short     bf16x8;
typedef __attribute__((ext_vector_type(4))) float     f32x4;
typedef __attribute__((ext_vector_type(2))) float     f32x2;
typedef __attribute__((ext_vector_type(4))) unsigned short u16x4;

#define OUT_STRIDE 1086
#define NS_STRIDE 1026
#define NS_BASE (4096*1086)

__device__ __forceinline__ unsigned short f2bf(float x) {
  unsigned int u = __float_as_uint(x);
  unsigned int r = (u + 0x7FFFu + ((u >> 16) & 1u)) >> 16;
  return (unsigned short)r;
}
__device__ __forceinline__ float bf2f(unsigned short u) {
  union { unsigned int i; float f; } v; v.i = ((unsigned int)u) << 16; return v.f;
}
__device__ __forceinline__ float sigmoidf(float x) { return 1.f / (1.f + expf(-x)); }

// ---------- transpose-convert R (1024 x 4096 f32) -> RbT (4096 x 1024 bf16) ----------
__global__ __launch_bounds__(256)
void transposeR(const float* __restrict__ R, unsigned short* __restrict__ Bt) {
  __shared__ float t[64][65];
  const int tx = threadIdx.x & 63, ty = threadIdx.x >> 6;
  const int j0 = blockIdx.x * 64, k0 = blockIdx.y * 64;
#pragma unroll
  for (int i = 0; i < 64; i += 4)
    t[ty + i][tx] = R[(size_t)(k0 + ty + i) * 4096 + j0 + tx];
  __syncthreads();
#pragma unroll
  for (int i = 0; i < 64; i += 4) {
    const int j = ty + i;
    Bt[(size_t)(j0 + j) * 1024 + k0 + tx] = f2bf(t[tx][j]);
  }
}

// ---------- convert h_tm1 -> bf16 ----------
__global__ __launch_bounds__(256)
void convertH(const float* __restrict__ states, unsigned short* __restrict__ hb) {
  const int idx = blockIdx.x * 256 + threadIdx.x;
  const int b = idx >> 8, u = (idx & 255) * 4;
  const float* sp = states + (size_t)b * 1026 + u;
  f32x2 v0 = *(const f32x2*)sp, v1 = *(const f32x2*)(sp + 2);
  u16x4 w;
  w[0] = f2bf(v0[0]); w[1] = f2bf(v0[1]); w[2] = f2bf(v1[0]); w[3] = f2bf(v1[1]);
  *(u16x4*)&hb[(size_t)b * 1024 + u] = w;
}

// ================= wave-independent 64x64 GEMM =================
// One 64-lane wave per block, owns a 64x64 output tile. MFMA fragments are
// loaded straight from global memory with per-lane addresses (16B/lane,
// 4 lanes/64B-line => fully-consumed lines). No LDS staging, no barriers.
// NBLK=2048: GEMM1 (N=2048, z|r epilogue). NBLK=1024: GEMM2/3 (N=1024).
template<int EPI, int NBLK>
__global__ __launch_bounds__(64, 2)
void gemm_w(const unsigned short* __restrict__ A,
            const unsigned short* __restrict__ Bt, int colbase,
            const int* __restrict__ chv,
            const float* __restrict__ states,
            const float* __restrict__ kcm,
            const float* __restrict__ kd,
            const float* __restrict__ bias_z,
            const float* __restrict__ bias,
            float* __restrict__ zbuf,
            unsigned short* __restrict__ rh,
            float* __restrict__ outp,
            unsigned short* __restrict__ hb2) {
  __shared__ int   chs[64];
  __shared__ float d0s[64], d1s[64];

  const int lane = threadIdx.x;
  const int arow = lane & 15, q = lane >> 4;

  // XCD-chunked decode: each XCD gets a contiguous (cm,cn) chunk so its
  // working set (A-panel + B-panel, 2-4 MB) stays L2-resident.
  int mt, nt;
  {
    const int xcd = blockIdx.x & 7, l = blockIdx.x >> 3;
    const int cm = xcd >> 1, cn = xcd & 1;
    if (NBLK == 2048) {            // grid 64m x 32n, chunks 16m x 16n
      mt = cm * 16 + (l & 15);
      nt = cn * 16 + (l >> 4);
    } else {                       // grid 64m x 16n, chunks 16m x 8n
      mt = cm * 16 + (l & 15);
      nt = cn * 8 + (l >> 4);
    }
  }
  const int m0 = mt * 64, n0 = nt * 64;

  chs[lane] = chv[m0 + lane];
  d0s[lane] = states[(size_t)(m0 + lane) * 1026 + 1024];
  d1s[lane] = states[(size_t)(m0 + lane) * 1026 + 1025];
  __syncthreads();

  // per-lane fragment bases (elements)
  const unsigned short* Al = A  + (size_t)(m0 + arow) * 1024 + q * 8;
  const unsigned short* Bl = Bt + (size_t)(colbase + n0 + arow) * 1024 + q * 8;

  f32x4 acc[4][4] = {};
  bf16x8 a0[4], b0[4], a1[4], b1[4];

#define LOADF(AF, BF, kk) {                                                    \
    _Pragma("unroll")                                                          \
    for (int mi = 0; mi < 4; ++mi)                                             \
      AF[mi] = *(const bf16x8*)(Al + (size_t)mi * 16384 + (kk));               \
    _Pragma("unroll")                                                          \
    for (int ni = 0; ni < 4; ++ni)                                             \
      BF[ni] = *(const bf16x8*)(Bl + (size_t)ni * 16384 + (kk)); }
#define MM(AF, BF) {                                                           \
    _Pragma("unroll")                                                          \
    for (int mi = 0; mi < 4; ++mi)                                             \
      _Pragma("unroll")                                                        \
      for (int ni = 0; ni < 4; ++ni)                                           \
        acc[mi][ni] = __builtin_amdgcn_mfma_f32_16x16x32_bf16(AF[mi], BF[ni], acc[mi][ni], 0, 0, 0); }

  LOADF(a0, b0, 0)
#pragma unroll
  for (int t = 0; t < 32; t += 2) {
    if (t + 1 < 32) LOADF(a1, b1, (t + 1) * 32)
    MM(a0, b0)
    if (t + 2 < 32) LOADF(a0, b0, (t + 2) * 32)
    if (t + 1 < 32) MM(a1, b1)
  }
#undef LOADF
#undef MM

  // ---------------- epilogue ----------------
#pragma unroll
  for (int mi = 0; mi < 4; ++mi) {
#pragma unroll
    for (int i = 0; i < 4; ++i) {
      const int lrow = mi * 16 + q * 4 + i;
      const int grow = m0 + lrow;
      const int ch = chs[lrow];
      const float d0 = d0s[lrow], d1 = d1s[lrow];
      const float* kcr = kcm + (size_t)ch * 4096;
#pragma unroll
      for (int ni = 0; ni < 4; ++ni) {
        const int gc = n0 + ni * 16 + arow;                     // col within this GEMM's N
        const float a = acc[mi][ni][i];
        if (EPI == 1) {
          const float pre = kcr[gc] + d0 * kd[gc] + d1 * kd[4096 + gc];
          if (n0 < 1024) {
            const float z = sigmoidf(a + pre + bias_z[gc]);
            zbuf[(size_t)grow * 1024 + gc] = z;
          } else {
            const int uc = gc - 1024;
            const float r = sigmoidf(a + pre + bias[uc]);
            rh[(size_t)grow * 1024 + uc] = f2bf(r * states[(size_t)grow * 1026 + uc]);
          }
        } else if (EPI == 2) {
          const int fullc = 2048 + gc;
          const float v = a + kcr[fullc] + d0 * kd[fullc] + d1 * kd[4096 + fullc] + bias[1024 + gc];
          const float hh = tanhf(v);
          const float z = zbuf[(size_t)grow * 1024 + gc];
          const float htm = states[(size_t)grow * 1026 + gc];
          const float h = z * htm + (1.f - z) * hh;
          outp[(size_t)grow * NS_STRIDE + gc] = h;
          hb2[(size_t)grow * 1024 + gc] = f2bf(h);
        } else {
          const int fullc = 3072 + gc;
          const float v = a + kcr[fullc] + d0 * kd[fullc] + d1 * kd[4096 + fullc] + bias[2048 + gc];
          outp[(size_t)grow * OUT_STRIDE + gc] = tanhf(v);
        }
      }
    }
  }
}

// ---------- GMM head ----------
__global__ __launch_bounds__(512)
void gmm_kernel(const float* __restrict__ obuf,
                const float* __restrict__ Wg,
                const float* __restrict__ bg,
                float* __restrict__ outp,
                float* __restrict__ ns) {
  __shared__ float Wl[128 * 60 + 16];
  __shared__ float ol[8 * 1024];
  const int tid = threadIdx.x;
  const int lane = tid & 63;
  const int wave = tid >> 6;
  const int row0 = blockIdx.x * 8;

  for (int i = tid; i < 4096; i += 512) {
    const int rr = i >> 9, c2 = (i & 511) * 2;
    *(f32x2*)&ol[rr * 1024 + c2] = *(const f32x2*)&obuf[(size_t)(row0 + rr) * OUT_STRIDE + c2];
  }

  float g = 0.f;
  for (int kc0 = 0; kc0 < 1024; kc0 += 128) {
    __syncthreads();
    for (int i = tid; i < 1920; i += 512)
      *(f32x4*)&Wl[i * 4] = *(const f32x4*)&Wg[kc0 * 60 + i * 4];
    __syncthreads();
    const float* orow = &ol[wave * 1024 + kc0];
#pragma unroll 8
    for (int k = 0; k < 128; ++k)
      g = fmaf(orow[k], Wl[k * 60 + lane], g);
  }
  if (lane < 60) g += bg[lane];

  float e = 0.f;
  if (lane < 20) e = fminf(fmaxf(expf(g), 1e-10f), 1e10f);
  float s = e;
#pragma unroll
  for (int m = 1; m < 32; m <<= 1) s += __shfl_xor(s, m, 64);
  const float pi = (lane < 20) ? e / s : 0.f;
  const int src1 = (lane < 20) ? lane + 20 : lane;
  const int src2 = (lane < 20) ? lane + 40 : lane;
  const float mux = __shfl(g, src1, 64);
  const float muy = __shfl(g, src2, 64);
  float px = pi * mux, py = pi * muy;
#pragma unroll
  for (int m = 1; m < 32; m <<= 1) { px += __shfl_xor(px, m, 64); py += __shfl_xor(py, m, 64); }

  const int row = row0 + wave;
  float* orow = outp + (size_t)row * OUT_STRIDE;
  if (lane < 20) orow[1024 + lane] = pi;
  else if (lane < 60) orow[1024 + lane] = g;
  if (lane == 0) {
    orow[1084] = px;
    orow[1085] = py;
    ns[(size_t)row * NS_STRIDE + 1024] = px;
    ns[(size_t)row * NS_STRIDE + 1025] = py;
  }
}

extern "C" void kernel_launch(void* const* d_in, const int* in_sizes, int n_in,
                              void* d_out, int out_size, void* d_ws, size_t ws_size,
                              hipStream_t stream) {
  const int*   chv    = (const int*)d_in[0];
  const float* states = (const float*)d_in[1];
  const float* bias_z = (const float*)d_in[2];
  const float* R      = (const float*)d_in[3];
  const float* kc     = (const float*)d_in[4];
  const float* bias   = (const float*)d_in[5];
  const float* kd     = (const float*)d_in[6];
  const float* Wg     = (const float*)d_in[7];
  const float* bg     = (const float*)d_in[8];
  float* out = (float*)d_out;

  char* ws = (char*)d_ws;
  unsigned short* RbT  = (unsigned short*)ws;                   // 8 MB
  unsigned short* hb   = (unsigned short*)(ws + 8388608);       // 8 MB
  unsigned short* rh   = (unsigned short*)(ws + 16777216);      // 8 MB
  unsigned short* hb2  = (unsigned short*)(ws + 25165824);      // 8 MB
  float*          zbuf = (float*)(ws + 33554432);               // 16 MB

  transposeR<<<dim3(64, 16), 256, 0, stream>>>(R, RbT);
  convertH<<<4096, 256, 0, stream>>>(states, hb);

  // GEMM1: N=2048 (z cols 0..1023, r cols 1024..2047), fused gate epilogue
  gemm_w<1, 2048><<<2048, 64, 0, stream>>>(hb, RbT, 0,
      chv, states, kc, kd, bias_z, bias, zbuf, rh, nullptr, nullptr);

  // GEMM2: hh -> h (new_state + h bf16)
  gemm_w<2, 1024><<<1024, 64, 0, stream>>>(rh, RbT, 2048,
      chv, states, kc, kd, bias_z, bias, zbuf, nullptr, out + NS_BASE, hb2);

  // GEMM3: o -> out
  gemm_w<3, 1024><<<1024, 64, 0, stream>>>(hb2, RbT, 3072,
      chv, states, kc, kd, bias_z, bias, nullptr, nullptr, out, nullptr);

  gmm_kernel<<<512, 512, 0, stream>>>(out, Wg, bg, out, out + NS_BASE);
}

// Round 10
// 310.199 us; speedup vs baseline: 1.4282x; 1.4282x over previous
//
#include <hip/hip_runtime.h>

typedef __attribute__((ext_vector_type(8))) short     bf16x8;
typedef __attribute__((ext_vector_type(4))) float     f32x4;
typedef __attribute__((ext_vector_type(2))) float     f32x2;
typedef __attribute__((ext_vector_type(4))) unsigned short u16x4;

#define OUT_STRIDE 1086
#define NS_STRIDE 1026
#define NS_BASE (4096*1086)

__device__ __forceinline__ unsigned short f2bf(float x) {
  unsigned int u = __float_as_uint(x);
  unsigned int r = (u + 0x7FFFu + ((u >> 16) & 1u)) >> 16;
  return (unsigned short)r;
}
__device__ __forceinline__ float bf2f(unsigned short u) {
  union { unsigned int i; float f; } v; v.i = ((unsigned int)u) << 16; return v.f;
}
__device__ __forceinline__ float sigmoidf(float x) { return 1.f / (1.f + expf(-x)); }

__device__ __forceinline__ void gld_lds16(const void* g, void* l) {
  __builtin_amdgcn_global_load_lds((const __attribute__((address_space(1))) void*)g,
                                   (__attribute__((address_space(3))) void*)l, 16, 0, 0);
}

// XCD-chunked decode for 32m x 16n grids (512 blocks).
__device__ __forceinline__ void decode_block(int bid, int& m0, int& n0) {
  const int swz = (bid & 7) * 64 + (bid >> 3);   // bijective: 512 % 8 == 0
  const int chunk = swz >> 6, l = swz & 63;
  m0 = ((chunk & 3) * 8 + (l >> 3)) * 128;
  n0 = ((chunk >> 2) * 8 + (l & 7)) * 64;
}

// ---------- transpose-convert R (1024 x 4096 f32) -> RbT (4096 x 1024 bf16) ----------
__global__ __launch_bounds__(256)
void transposeR(const float* __restrict__ R, unsigned short* __restrict__ Bt) {
  __shared__ float t[64][65];
  const int tx = threadIdx.x & 63, ty = threadIdx.x >> 6;
  const int j0 = blockIdx.x * 64, k0 = blockIdx.y * 64;
#pragma unroll
  for (int i = 0; i < 64; i += 4)
    t[ty + i][tx] = R[(size_t)(k0 + ty + i) * 4096 + j0 + tx];
  __syncthreads();
#pragma unroll
  for (int i = 0; i < 64; i += 4) {
    const int j = ty + i;
    Bt[(size_t)(j0 + j) * 1024 + k0 + tx] = f2bf(t[tx][j]);
  }
}

// ---------- convert h_tm1 -> bf16 ----------
__global__ __launch_bounds__(256)
void convertH(const float* __restrict__ states, unsigned short* __restrict__ hb) {
  const int idx = blockIdx.x * 256 + threadIdx.x;
  const int b = idx >> 8, u = (idx & 255) * 4;
  const float* sp = states + (size_t)b * 1026 + u;
  f32x2 v0 = *(const f32x2*)sp, v1 = *(const f32x2*)(sp + 2);
  u16x4 w;
  w[0] = f2bf(v0[0]); w[1] = f2bf(v0[1]); w[2] = f2bf(v1[0]); w[3] = f2bf(v1[1]);
  *(u16x4*)&hb[(size_t)b * 1024 + u] = w;
}

// ---------- Wg (1024x60 f32) -> WgT (64x1024 bf16, rows 60..63 zero) ----------
__global__ __launch_bounds__(256)
void prep_wgt(const float* __restrict__ Wg, unsigned short* __restrict__ WgT) {
  const int idx = blockIdx.x * 256 + threadIdx.x;   // 16384 threads
  const int c = idx & 63, kq = idx >> 6;            // kq in [0,256)
#pragma unroll
  for (int j = 0; j < 4; ++j) {
    const int k = kq * 4 + j;
    WgT[(size_t)c * 1024 + k] = (c < 60) ? f2bf(Wg[(size_t)k * 60 + c]) : (unsigned short)0;
  }
}

// ---------- GEMM1 fused: z (f32) + rh (bf16). 4-buffer depth-2 pipeline ----------
__global__ __launch_bounds__(256)
void gemm_zr(const unsigned short* __restrict__ A,
             const unsigned short* __restrict__ Bt,
             const int* __restrict__ chv,
             const float* __restrict__ states,
             const float* __restrict__ kc,
             const float* __restrict__ kd,
             const float* __restrict__ bias_z,
             const float* __restrict__ bias,
             float* __restrict__ zbuf,
             unsigned short* __restrict__ rh) {
  __shared__ unsigned short Al[4][128 * 32];
  __shared__ unsigned short Bzl[4][64 * 32];
  __shared__ unsigned short Brl[4][64 * 32];
  __shared__ int   chs[128];
  __shared__ float d0s[128], d1s[128];

  const int tid = threadIdx.x, lane = tid & 63, wave = tid >> 6;
  int m0, n0;
  decode_block(blockIdx.x, m0, n0);

  if (tid < 128) {
    const int r = m0 + tid;
    chs[tid] = chv[r];
    d0s[tid] = states[(size_t)r * 1026 + 1024];
    d1s[tid] = states[(size_t)r * 1026 + 1025];
  }

  const unsigned short* Ag  = A  + (size_t)m0 * 1024;
  const unsigned short* Bzg = Bt + (size_t)n0 * 1024;
  const unsigned short* Brg = Bt + (size_t)(1024 + n0) * 1024;

  const int c1 = tid + 256;
  const int ar0 = tid >> 2, ak0 = (tid & 3) * 8;
  const int ar1 = c1 >> 2,  ak1 = (c1 & 3) * 8;

  f32x4 accz[2][4] = {}, accr[2][4] = {};
  const int arow = lane & 15, kg = (lane >> 4) * 8;

#define STAGE_ZR(b, kk)                                                        \
  gld_lds16(Ag  + (size_t)ar0 * 1024 + (kk) + ak0, &Al[b][tid * 8]);           \
  gld_lds16(Ag  + (size_t)ar1 * 1024 + (kk) + ak1, &Al[b][c1 * 8]);            \
  gld_lds16(Bzg + (size_t)ar0 * 1024 + (kk) + ak0, &Bzl[b][tid * 8]);          \
  gld_lds16(Brg + (size_t)ar0 * 1024 + (kk) + ak0, &Brl[b][tid * 8]);

  auto compute = [&](int cb) {
    bf16x8 af[2], bzf[4], brf[4];
#pragma unroll
    for (int mi = 0; mi < 2; ++mi)
      af[mi] = *(const bf16x8*)&Al[cb][(wave * 32 + mi * 16 + arow) * 32 + kg];
#pragma unroll
    for (int ni = 0; ni < 4; ++ni) {
      bzf[ni] = *(const bf16x8*)&Bzl[cb][(ni * 16 + arow) * 32 + kg];
      brf[ni] = *(const bf16x8*)&Brl[cb][(ni * 16 + arow) * 32 + kg];
    }
    __builtin_amdgcn_s_setprio(1);
#pragma unroll
    for (int mi = 0; mi < 2; ++mi)
#pragma unroll
      for (int ni = 0; ni < 4; ++ni) {
        accz[mi][ni] = __builtin_amdgcn_mfma_f32_16x16x32_bf16(af[mi], bzf[ni], accz[mi][ni], 0, 0, 0);
        accr[mi][ni] = __builtin_amdgcn_mfma_f32_16x16x32_bf16(af[mi], brf[ni], accr[mi][ni], 0, 0, 0);
      }
    __builtin_amdgcn_s_setprio(0);
  };

  STAGE_ZR(0, 0);
  STAGE_ZR(1, 32);
  for (int t = 0; t < 30; ++t) {
    const int nx = (t + 2) & 3;
    STAGE_ZR(nx, (t + 2) * 32);
    asm volatile("s_waitcnt vmcnt(8)" ::: "memory");
    __builtin_amdgcn_s_barrier();
    asm volatile("" ::: "memory");
    compute(t & 3);
  }
  asm volatile("s_waitcnt vmcnt(4)" ::: "memory");
  __builtin_amdgcn_s_barrier();
  asm volatile("" ::: "memory");
  compute(2);
  asm volatile("s_waitcnt vmcnt(0)" ::: "memory");
  __builtin_amdgcn_s_barrier();
  asm volatile("" ::: "memory");
  compute(3);
#undef STAGE_ZR

#pragma unroll
  for (int mi = 0; mi < 2; ++mi) {
#pragma unroll
    for (int r = 0; r < 4; ++r) {
      const int lrow = wave * 32 + mi * 16 + (lane >> 4) * 4 + r;
      const int grow = m0 + lrow;
      const int ch = chs[lrow];
      const float d0 = d0s[lrow], d1 = d1s[lrow];
      const float* kcrow = kc + (size_t)ch * 4096;
#pragma unroll
      for (int ni = 0; ni < 4; ++ni) {
        const int jc = n0 + ni * 16 + (lane & 15);
        const float vz = accz[mi][ni][r] + kcrow[jc]
                       + d0 * kd[jc] + d1 * kd[4096 + jc] + bias_z[jc];
        const float vr = accr[mi][ni][r] + kcrow[1024 + jc]
                       + d0 * kd[1024 + jc] + d1 * kd[4096 + 1024 + jc] + bias[jc];
        const float z = sigmoidf(vz);
        const float rr = sigmoidf(vr);
        zbuf[(size_t)grow * 1024 + jc] = z;
        rh[(size_t)grow * 1024 + jc] = f2bf(rr * bf2f(A[(size_t)grow * 1024 + jc]));
      }
    }
  }
}

// ---------- GEMM 2/3: 128x64 tile, 4-buffer depth-2 pipeline ----------
// EPI 2: hh->h (writes ns f32 + h bf16).  EPI 3: o (writes out f32 + o bf16).
template<int EPI>
__global__ __launch_bounds__(256)
void gemm_k(const unsigned short* __restrict__ A,
            const unsigned short* __restrict__ Bt,
            const int* __restrict__ chv,
            const float* __restrict__ states,
            const float* __restrict__ kc, int colbase,
            const float* __restrict__ kd,
            const float* __restrict__ bias, int biasoff,
            const float* __restrict__ zbuf,
            float* __restrict__ out2,
            unsigned short* __restrict__ hb2) {
  __shared__ unsigned short Al[4][128 * 32];
  __shared__ unsigned short Bl[4][64 * 32];
  __shared__ int   chs[128];
  __shared__ float d0s[128], d1s[128];

  const int tid = threadIdx.x, lane = tid & 63, wave = tid >> 6;
  int m0, n0;
  decode_block(blockIdx.x, m0, n0);

  if (tid < 128) {
    const int r = m0 + tid;
    chs[tid] = chv[r];
    d0s[tid] = states[(size_t)r * 1026 + 1024];
    d1s[tid] = states[(size_t)r * 1026 + 1025];
  }

  const unsigned short* Ag = A  + (size_t)m0 * 1024;
  const unsigned short* Bg = Bt + (size_t)n0 * 1024;

  const int c1 = tid + 256;
  const int ar0 = tid >> 2, ak0 = (tid & 3) * 8;
  const int ar1 = c1 >> 2,  ak1 = (c1 & 3) * 8;

  f32x4 acc[2][4] = {};
  const int arow = lane & 15, kg = (lane >> 4) * 8;

#define STAGE_K(b, kk)                                                         \
  gld_lds16(Ag + (size_t)ar0 * 1024 + (kk) + ak0, &Al[b][tid * 8]);            \
  gld_lds16(Ag + (size_t)ar1 * 1024 + (kk) + ak1, &Al[b][c1 * 8]);             \
  gld_lds16(Bg + (size_t)ar0 * 1024 + (kk) + ak0, &Bl[b][tid * 8]);

  auto compute = [&](int cb) {
    bf16x8 af[2], bfr[4];
#pragma unroll
    for (int mi = 0; mi < 2; ++mi)
      af[mi] = *(const bf16x8*)&Al[cb][(wave * 32 + mi * 16 + arow) * 32 + kg];
#pragma unroll
    for (int ni = 0; ni < 4; ++ni)
      bfr[ni] = *(const bf16x8*)&Bl[cb][(ni * 16 + arow) * 32 + kg];
    __builtin_amdgcn_s_setprio(1);
#pragma unroll
    for (int mi = 0; mi < 2; ++mi)
#pragma unroll
      for (int ni = 0; ni < 4; ++ni)
        acc[mi][ni] = __builtin_amdgcn_mfma_f32_16x16x32_bf16(af[mi], bfr[ni], acc[mi][ni], 0, 0, 0);
    __builtin_amdgcn_s_setprio(0);
  };

  STAGE_K(0, 0);
  STAGE_K(1, 32);
  for (int t = 0; t < 30; ++t) {
    const int nx = (t + 2) & 3;
    STAGE_K(nx, (t + 2) * 32);
    asm volatile("s_waitcnt vmcnt(6)" ::: "memory");
    __builtin_amdgcn_s_barrier();
    asm volatile("" ::: "memory");
    compute(t & 3);
  }
  asm volatile("s_waitcnt vmcnt(3)" ::: "memory");
  __builtin_amdgcn_s_barrier();
  asm volatile("" ::: "memory");
  compute(2);
  asm volatile("s_waitcnt vmcnt(0)" ::: "memory");
  __builtin_amdgcn_s_barrier();
  asm volatile("" ::: "memory");
  compute(3);
#undef STAGE_K

#pragma unroll
  for (int mi = 0; mi < 2; ++mi) {
#pragma unroll
    for (int r = 0; r < 4; ++r) {
      const int lrow = wave * 32 + mi * 16 + (lane >> 4) * 4 + r;
      const int grow = m0 + lrow;
      const int ch = chs[lrow];
      const float d0 = d0s[lrow], d1 = d1s[lrow];
      const float* kcrow = kc + (size_t)ch * 4096 + colbase;
#pragma unroll
      for (int ni = 0; ni < 4; ++ni) {
        const int gcol = n0 + ni * 16 + (lane & 15);
        float v = acc[mi][ni][r] + kcrow[gcol]
                + d0 * kd[colbase + gcol] + d1 * kd[4096 + colbase + gcol]
                + bias[biasoff + gcol];
        if (EPI == 2) {
          const float hh = tanhf(v);
          const float z = zbuf[(size_t)grow * 1024 + gcol];
          const float htm = states[(size_t)grow * 1026 + gcol];
          const float h = z * htm + (1.f - z) * hh;
          out2[(size_t)grow * NS_STRIDE + gcol] = h;
          hb2[(size_t)grow * 1024 + gcol] = f2bf(h);
        } else {
          const float o = tanhf(v);
          out2[(size_t)grow * OUT_STRIDE + gcol] = o;
          hb2[(size_t)grow * 1024 + gcol] = f2bf(o);   // bf16 o for the MFMA gmm head
        }
      }
    }
  }
}

// ---------- MFMA GMM head: gmm = o @ WgT^T + bg; softmax; preds ----------
// 256 blocks x 4 waves. Block = 16 rows; wave w covers K in [w*256, w*256+256).
// C layout per wave: row = q*4+i, col = ni*16+arow.
__global__ __launch_bounds__(256)
void gmm2(const unsigned short* __restrict__ ob,    // bf16 o [4096][1024]
          const unsigned short* __restrict__ WgT,   // bf16 [64][1024]
          const float* __restrict__ bg,             // [60]
          float* __restrict__ outp,
          float* __restrict__ ns) {
  __shared__ float red[3 * 16 * 64];
  const int tid = threadIdx.x, lane = tid & 63, wave = tid >> 6;
  const int arow = lane & 15, q = lane >> 4;
  const int r0 = blockIdx.x * 16;

  const unsigned short* Al = ob  + (size_t)(r0 + arow) * 1024 + q * 8 + wave * 256;
  const unsigned short* Bl = WgT + (size_t)arow * 1024 + q * 8 + wave * 256;

  f32x4 acc[4] = {};
#pragma unroll
  for (int t = 0; t < 8; ++t) {
    const bf16x8 af = *(const bf16x8*)(Al + t * 32);
#pragma unroll
    for (int ni = 0; ni < 4; ++ni) {
      const bf16x8 bf_ = *(const bf16x8*)(Bl + (size_t)ni * 16 * 1024 + t * 32);
      acc[ni] = __builtin_amdgcn_mfma_f32_16x16x32_bf16(af, bf_, acc[ni], 0, 0, 0);
    }
  }

  if (wave) {
#pragma unroll
    for (int ni = 0; ni < 4; ++ni)
#pragma unroll
      for (int i = 0; i < 4; ++i)
        red[(wave - 1) * 1024 + (ni * 4 + i) * 64 + lane] = acc[ni][i];
  }
  __syncthreads();
  if (wave == 0) {
#pragma unroll
    for (int w = 0; w < 3; ++w)
#pragma unroll
      for (int ni = 0; ni < 4; ++ni)
#pragma unroll
        for (int i = 0; i < 4; ++i)
          acc[ni][i] += red[w * 1024 + (ni * 4 + i) * 64 + lane];

    const int gb = lane & 48;   // q*16
#pragma unroll
    for (int i = 0; i < 4; ++i) {
      float g0 = acc[0][i] + bg[arow];
      float g1 = acc[1][i] + ((16 + arow < 60) ? bg[16 + arow] : 0.f);
      float g2 = acc[2][i] + ((32 + arow < 60) ? bg[32 + arow] : 0.f);
      float g3 = acc[3][i] + ((48 + arow < 60) ? bg[48 + arow] : 0.f);

      const float e0 = fminf(fmaxf(expf(g0), 1e-10f), 1e10f);
      const float e1 = (arow < 4) ? fminf(fmaxf(expf(g1), 1e-10f), 1e10f) : 0.f;
      float s = e0 + e1;
#pragma unroll
      for (int m = 1; m < 16; m <<= 1) s += __shfl_xor(s, m, 64);
      const float pi0 = e0 / s;
      const float pi1 = e1 / s;

      // mux_j (j = arow): col 20+arow -> g1@(arow+4) if arow<12 else g2@(arow-12)
      const float t1 = __shfl(g1, gb | ((arow + 4) & 15), 64);
      const float t2 = __shfl(g2, gb | ((arow + 4) & 15), 64);   // (arow-12)&15 == (arow+4)&15
      const float muxA = (arow < 12) ? t1 : t2;
      const float muxB = t2;                                      // col 36+arow (arow<4): g2@(arow+4)
      // muy_j (j = arow): col 40+arow -> g2@(arow+8) if arow<8 else g3@(arow-8)
      const float u1 = __shfl(g2, gb | ((arow + 8) & 15), 64);
      const float u2 = __shfl(g3, gb | ((arow + 8) & 15), 64);
      const float muyA = (arow < 8) ? u1 : u2;
      const float muyB = u2;                                      // col 56+arow (arow<4): g3@(arow+8)

      float px = pi0 * muxA + ((arow < 4) ? pi1 * muxB : 0.f);
      float py = pi0 * muyA + ((arow < 4) ? pi1 * muyB : 0.f);
#pragma unroll
      for (int m = 1; m < 16; m <<= 1) {
        px += __shfl_xor(px, m, 64);
        py += __shfl_xor(py, m, 64);
      }

      const int row = r0 + q * 4 + i;
      float* orow = outp + (size_t)row * OUT_STRIDE;
      orow[1024 + arow] = pi0;                       // pi cols 0-15
      if (arow < 4)  orow[1040 + arow] = pi1;        // pi cols 16-19
      if (arow >= 4) orow[1040 + arow] = g1;         // gmm cols 20-31
      orow[1056 + arow] = g2;                        // gmm cols 32-47
      if (arow < 12) orow[1072 + arow] = g3;         // gmm cols 48-59
      if (arow == 0) {
        orow[1084] = px;
        orow[1085] = py;
        ns[(size_t)row * NS_STRIDE + 1024] = px;
        ns[(size_t)row * NS_STRIDE + 1025] = py;
      }
    }
  }
}

extern "C" void kernel_launch(void* const* d_in, const int* in_sizes, int n_in,
                              void* d_out, int out_size, void* d_ws, size_t ws_size,
                              hipStream_t stream) {
  const int*   chv    = (const int*)d_in[0];
  const float* states = (const float*)d_in[1];
  const float* bias_z = (const float*)d_in[2];
  const float* R      = (const float*)d_in[3];
  const float* kc     = (const float*)d_in[4];
  const float* bias   = (const float*)d_in[5];
  const float* kd     = (const float*)d_in[6];
  const float* Wg     = (const float*)d_in[7];
  const float* bg     = (const float*)d_in[8];
  float* out = (float*)d_out;

  char* ws = (char*)d_ws;
  unsigned short* RbT  = (unsigned short*)ws;                   // 8 MB
  unsigned short* hb   = (unsigned short*)(ws + 8388608);       // 8 MB (reused as bf16 o)
  unsigned short* rh   = (unsigned short*)(ws + 16777216);      // 8 MB
  unsigned short* hb2  = (unsigned short*)(ws + 25165824);      // 8 MB
  float*          zbuf = (float*)(ws + 33554432);               // 16 MB
  unsigned short* WgT  = (unsigned short*)(ws + 50331648);      // 128 KB

  transposeR<<<dim3(64, 16), 256, 0, stream>>>(R, RbT);
  convertH<<<4096, 256, 0, stream>>>(states, hb);
  prep_wgt<<<64, 256, 0, stream>>>(Wg, WgT);

  gemm_zr<<<512, 256, 0, stream>>>(hb, RbT, chv, states, kc, kd, bias_z, bias, zbuf, rh);

  gemm_k<2><<<512, 256, 0, stream>>>(rh, RbT + (size_t)2048 * 1024,
      chv, states, kc, 2048, kd, bias, 1024, zbuf, out + NS_BASE, hb2);

  // GEMM3: writes f32 o into out AND bf16 o into hb (free after GEMM1)
  gemm_k<3><<<512, 256, 0, stream>>>(hb2, RbT + (size_t)3072 * 1024,
      chv, states, kc, 3072, kd, bias, 2048, nullptr, out, hb);

  gmm2<<<256, 256, 0, stream>>>(hb, WgT, bg, out, out + NS_BASE);
}